// Round 12
// baseline (858.550 us; speedup 1.0000x reference)
//
#include <hip/hip_runtime.h>
#include <hip/hip_bf16.h>

#ifndef __has_builtin
#define __has_builtin(x) 0
#endif

#define GG 128
#define SLOPE 0.01f
#define CHUNK 8192
#define NPB 64   // nodes per block in k_step
#define NREP 64  // accumulator replicas (atomic contention striping)

// wcat element offsets (f32 staged weights)
#define OFF_Wm   0
#define OFF_bm   3072
#define OFF_Wa   3168
#define OFF_ba   12384
#define OFF_Wg   12480
#define OFF_bg   12576
#define OFF_Wf   12592
#define OFF_bf   15664
#define OFF_Wt   15760
#define OFF_bt   21904
#define OFF_Wa1  22000
#define OFF_ba1  22032
#define WCAT_N   22048

__device__ __forceinline__ float lrelu(float v) { return v > 0.f ? v : SLOPE * v; }
__device__ __forceinline__ float b2f(__hip_bfloat16 v) { return __bfloat162float(v); }

__device__ __forceinline__ float ldf(const void* p, int i, int isf) {
    if (isf) return ((const float*)p)[i];
    return __bfloat162float(((const __hip_bfloat16*)p)[i]);
}
__device__ __forceinline__ void stf(void* p, int i, float v, int isf) {
    if (isf) ((float*)p)[i] = v;
    else ((__hip_bfloat16*)p)[i] = __float2bfloat16(v);
}

// ---------------- fp8 e4m3 (OCP) codec ----------------
// decode 4 fp8 bytes of a u32 -> 4 floats
__device__ __forceinline__ void fp8unpk(unsigned u, float* f) {
#if __has_builtin(__builtin_amdgcn_cvt_pk_f32_fp8)
    typedef float v2f __attribute__((ext_vector_type(2)));
    v2f lo = __builtin_amdgcn_cvt_pk_f32_fp8(u, false);
    v2f hi = __builtin_amdgcn_cvt_pk_f32_fp8(u, true);
    f[0] = lo[0]; f[1] = lo[1]; f[2] = hi[0]; f[3] = hi[1];
#else
    for (int b = 0; b < 4; ++b) {
        unsigned char x = (u >> (8 * b)) & 0xFF;
        unsigned s = x >> 7, e = (x >> 3) & 0xF, m = x & 7;
        float v;
        if (e == 0) v = ldexpf((float)m, -9);
        else v = ldexpf((float)(8 + m), (int)e - 10);
        f[b] = s ? -v : v;
    }
#endif
}
// encode f32 -> fp8 e4m3 byte (RNE, saturating)
__device__ __forceinline__ unsigned char fp8enc(float fv) {
#if __has_builtin(__builtin_amdgcn_cvt_pk_fp8_f32)
    int r = __builtin_amdgcn_cvt_pk_fp8_f32(fv, fv, 0, false);
    return (unsigned char)(r & 0xFF);
#else
    unsigned s = __float_as_uint(fv) >> 31;
    float af = fabsf(fv);
    if (!(af == af)) return 0x7F;
    if (af >= 448.f) return (unsigned char)((s << 7) | 0x7E);
    if (af == 0.f) return (unsigned char)(s << 7);
    int eb = (int)(__float_as_uint(af) >> 23) - 127;
    int step_e = (eb < -6) ? -9 : eb - 3;
    float q = rintf(ldexpf(af, -step_e));
    q = ldexpf(q, step_e);
    if (q == 0.f) return (unsigned char)(s << 7);
    if (q >= 448.f) return (unsigned char)((s << 7) | 0x7E);
    int e2 = (int)(__float_as_uint(q) >> 23) - 127;
    unsigned char out;
    if (e2 < -6) out = (unsigned char)((unsigned)rintf(ldexpf(q, 9)) & 7);
    else out = (unsigned char)(((e2 + 7) << 3) | ((__float_as_uint(q) >> 20) & 7));
    return (unsigned char)(out | (s << 7));
#endif
}

// ---------------- dtype detection ----------------
__global__ void k_detect(const unsigned short* __restrict__ w, int n, int* __restrict__ flag) {
    __shared__ int bad;
    if (threadIdx.x == 0) bad = 0;
    __syncthreads();
    for (int t = threadIdx.x; t < n; t += 256) {
        unsigned short u = w[t];
        int e = (u >> 7) & 0xFF;
        if (e >= 141) bad = 1;  // benign same-value race
    }
    __syncthreads();
    if (threadIdx.x == 0) { flag[0] = bad; flag[32] = 1; }
}

// ---------------- one-shot weight staging to f32 ----------------
struct CvtArgs {
    const void* p[12];
    int off[12];
    int n[12];
};
__global__ void k_cvt_all(CvtArgs a, float* __restrict__ dst, const int* __restrict__ dtf) {
    int isf = *dtf;
    int seg = blockIdx.y;
    int i = blockIdx.x * 256 + threadIdx.x;
    if (i < a.n[seg]) dst[a.off[seg] + i] = ldf(a.p[seg], i, isf);
}

// ---------------- embed + step-0 message (fused; m fp8 node-major) ----------------
__global__ void k_embed_msg(const void* __restrict__ nf, const void* __restrict__ We,
                            const void* __restrict__ be,
                            const float* __restrict__ Wm0, const float* __restrict__ bm0,
                            float* __restrict__ x, unsigned char* __restrict__ m, int N,
                            const int* __restrict__ dtf) {
    __shared__ float WL[1024];
    __shared__ float WeL[32], beL[32], bmL[32];
    __shared__ float xs[8][32];
    int isf = *dtf;
    int tid = threadIdx.x;
    for (int t = tid; t < 1024; t += 256) WL[t] = Wm0[t];
    if (tid < 32) { WeL[tid] = ldf(We, tid, isf); beL[tid] = ldf(be, tid, isf); bmL[tid] = bm0[tid]; }
    int s = tid >> 5, j = tid & 31;
    int n = blockIdx.x * 8 + s;
    __syncthreads();
    float xv = 0.f;
    if (n < N) {
        xv = lrelu(ldf(nf, n, isf) * WeL[j] + beL[j]);
        x[n * 32 + j] = xv;
        xs[s][j] = xv;
    }
    __syncthreads();
    if (n >= N) return;
    float acc = bmL[j];
#pragma unroll
    for (int k = 0; k < 32; ++k) acc += xs[s][k] * WL[k * 32 + j];
    m[n * 32 + j] = fp8enc(lrelu(acc));
}

// ---------------- graph offsets from sorted batch ----------------
__global__ void k_graph_off(const int* __restrict__ batch, int* __restrict__ goff, int N) {
    int n = blockIdx.x * 256 + threadIdx.x;
    if (n >= N) return;
    int bn = batch[n];
    if (n == 0) {
        for (int g = 0; g <= bn; ++g) goff[g] = 0;
    } else {
        int bp = batch[n - 1];
        for (int g = bp + 1; g <= bn; ++g) goff[g] = n;
    }
    if (n == N - 1) {
        for (int g = bn + 1; g <= GG; ++g) goff[g] = N;
    }
}

// ---------------- fallback CSR build (B > 2048 only) ----------------
__global__ void k_hist(const int* __restrict__ dst, unsigned* __restrict__ deg, int E) {
    int e = blockIdx.x * 256 + threadIdx.x;
    if (e >= E) return;
    atomicAdd(&deg[dst[e]], 1u);
}
__global__ void k_scan1(const unsigned* __restrict__ deg, unsigned* __restrict__ excl,
                        unsigned* __restrict__ bsum, int N) {
    __shared__ unsigned s[256];
    int i = blockIdx.x * 256 + threadIdx.x;
    unsigned v = (i < N) ? deg[i] : 0u;
    s[threadIdx.x] = v;
    __syncthreads();
    for (int off = 1; off < 256; off <<= 1) {
        unsigned t = (threadIdx.x >= (unsigned)off) ? s[threadIdx.x - off] : 0u;
        __syncthreads();
        s[threadIdx.x] += t;
        __syncthreads();
    }
    if (i < N) excl[i] = s[threadIdx.x] - v;
    if (threadIdx.x == 255) bsum[blockIdx.x] = s[255];
}
__global__ void k_scan2(const unsigned* __restrict__ bsum, unsigned* __restrict__ boff, int nb) {
    __shared__ unsigned s[256];
    __shared__ unsigned carry;
    if (threadIdx.x == 0) carry = 0u;
    __syncthreads();
    for (int base = 0; base < nb; base += 256) {
        int i = base + threadIdx.x;
        unsigned v = (i < nb) ? bsum[i] : 0u;
        s[threadIdx.x] = v;
        __syncthreads();
        for (int off = 1; off < 256; off <<= 1) {
            unsigned t = (threadIdx.x >= (unsigned)off) ? s[threadIdx.x - off] : 0u;
            __syncthreads();
            s[threadIdx.x] += t;
            __syncthreads();
        }
        if (i < nb) boff[i] = carry + s[threadIdx.x] - v;
        __syncthreads();
        if (threadIdx.x == 0) carry += s[255];
        __syncthreads();
    }
}
__global__ void k_scan3(unsigned* __restrict__ indptr, const unsigned* __restrict__ boff,
                        unsigned* __restrict__ cursor, int N, int E) {
    int i = blockIdx.x * 256 + threadIdx.x;
    if (i >= N) return;
    unsigned v = indptr[i] + boff[i >> 8];
    indptr[i] = v;
    cursor[i] = v;
    if (i == 0) indptr[N] = (unsigned)E;
}
__global__ void k_scatter(const int* __restrict__ src, const int* __restrict__ dst,
                          unsigned* __restrict__ cursor, unsigned* __restrict__ ssrc, int E) {
    int e = blockIdx.x * 256 + threadIdx.x;
    if (e >= E) return;
    unsigned pos = atomicAdd(&cursor[dst[e]], 1u);
    ssrc[pos] = (unsigned)src[e];
}

// ---------------- bucketed CSR build ----------------
__global__ void k_bhist(const int* __restrict__ dst, unsigned* __restrict__ bcnt, int E, int B) {
    __shared__ unsigned h[2048];
    for (int t = threadIdx.x; t < B; t += 256) h[t] = 0;
    __syncthreads();
    int start = blockIdx.x * CHUNK, end = min(E, start + CHUNK);
    for (int e = start + threadIdx.x; e < end; e += 256)
        atomicAdd(&h[dst[e] >> 8], 1u);
    __syncthreads();
    for (int t = threadIdx.x; t < B; t += 256)
        if (h[t]) atomicAdd(&bcnt[t], h[t]);
}

__global__ void k_bscan(const unsigned* __restrict__ bcnt, unsigned* __restrict__ bbase,
                        unsigned* __restrict__ bcur, int B, int E) {
    __shared__ unsigned s[256];
    __shared__ unsigned carry;
    if (threadIdx.x == 0) carry = 0u;
    __syncthreads();
    for (int base = 0; base < B; base += 256) {
        int i = base + threadIdx.x;
        unsigned v = (i < B) ? bcnt[i] : 0u;
        s[threadIdx.x] = v;
        __syncthreads();
        for (int off = 1; off < 256; off <<= 1) {
            unsigned t = (threadIdx.x >= (unsigned)off) ? s[threadIdx.x - off] : 0u;
            __syncthreads();
            s[threadIdx.x] += t;
            __syncthreads();
        }
        if (i < B) {
            unsigned ex = carry + s[threadIdx.x] - v;
            bbase[i] = ex;
            bcur[i] = ex;
        }
        __syncthreads();
        if (threadIdx.x == 0) carry += s[255];
        __syncthreads();
    }
    if (threadIdx.x == 0) bbase[B] = (unsigned)E;
}

__global__ void k_binA(const int* __restrict__ src, const int* __restrict__ dst,
                       unsigned* __restrict__ bcur, unsigned long long* __restrict__ packed,
                       int E, int B) {
    __shared__ unsigned h[2048];
    __shared__ unsigned pos[2048];
    for (int t = threadIdx.x; t < B; t += 256) h[t] = 0;
    __syncthreads();
    int start = blockIdx.x * CHUNK, end = min(E, start + CHUNK);
    for (int e = start + threadIdx.x; e < end; e += 256)
        atomicAdd(&h[dst[e] >> 8], 1u);
    __syncthreads();
    for (int t = threadIdx.x; t < B; t += 256)
        pos[t] = h[t] ? atomicAdd(&bcur[t], h[t]) : 0u;
    __syncthreads();
    for (int e = start + threadIdx.x; e < end; e += 256) {
        int d = dst[e];
        unsigned p = atomicAdd(&pos[d >> 8], 1u);
        packed[p] = ((unsigned long long)(unsigned)d << 32) | (unsigned)src[e];
    }
}

// per-bucket: LDS degree count + scan -> indptr, then bucket-local scatter
__global__ void k_csr(const unsigned long long* __restrict__ packed,
                      const unsigned* __restrict__ bbase,
                      unsigned* __restrict__ indptr,
                      unsigned* __restrict__ ssrc, int N, int E) {
    __shared__ unsigned deg[256];
    __shared__ unsigned scn[256];
    __shared__ unsigned cur[256];
    int g = blockIdx.x, tid = threadIdx.x;
    int n0 = g << 8;
    int cnt = min(256, N - n0);
    deg[tid] = 0;
    __syncthreads();
    unsigned e0 = bbase[g], e1 = bbase[g + 1];
    for (unsigned e = e0 + tid; e < e1; e += 256) {
        int d = (int)(packed[e] >> 32);
        atomicAdd(&deg[d - n0], 1u);
    }
    __syncthreads();
    unsigned v = deg[tid];
    scn[tid] = v;
    __syncthreads();
    for (int off = 1; off < 256; off <<= 1) {
        unsigned t = (tid >= off) ? scn[tid - off] : 0u;
        __syncthreads();
        scn[tid] += t;
        __syncthreads();
    }
    unsigned start = e0 + scn[tid] - v;
    if (tid < cnt) { indptr[n0 + tid] = start; cur[tid] = start; }
    if (g == (int)gridDim.x - 1 && tid == 0) indptr[N] = (unsigned)E;
    __syncthreads();
    for (unsigned e = e0 + tid; e < e1; e += 256) {
        unsigned long long pk = packed[e];
        int d = (int)(pk >> 32);
        unsigned p = atomicAdd(&cur[d - n0], 1u);
        ssrc[p] = (unsigned)pk;
    }
}

// ---------------- fused step (fp8 gather + GlobalAttention, striped accumulators) --------
// Gather: 2 lanes/edge, 16 edge slots, uint4 (16 fp8) loads -> 32B/row total.
// Then f_agg -> gate/a1 logits -> feat matmul, U += e*feat, S += e (reg-accumulated,
// flushed to replica blockIdx&63).
__global__ void k_step(float* __restrict__ x, const unsigned char* __restrict__ m_in,
                       unsigned char* __restrict__ m_out,
                       const float* __restrict__ xg, const int* __restrict__ batch,
                       const unsigned* __restrict__ indptr, const unsigned* __restrict__ ssrc,
                       const float* __restrict__ Wa, const float* __restrict__ ba,
                       const float* __restrict__ Wg, const float* __restrict__ bg,
                       const float* __restrict__ Wa1, const float* __restrict__ ba1,
                       const float* __restrict__ Wf, const float* __restrict__ bf,
                       const float* __restrict__ Wm_nx, const float* __restrict__ bm_nx,
                       float* __restrict__ la1, float* __restrict__ U, float* __restrict__ S,
                       int N, int hasNext) {
    __shared__ float WL[3072];
    __shared__ float WmL[1024];
    __shared__ float WfL[1024];
    __shared__ float zL[8][96];
    __shared__ float xnL[8][32];
    __shared__ float baL[32], WgL[32], W1L[32], bmL[32], bfL[32];
    __shared__ float bgL, b1L;
    int tid = threadIdx.x;
    for (int t = tid; t < 3072; t += 256) WL[t] = Wa[t];
    for (int t = tid; t < 1024; t += 256) WfL[t] = Wf[t];
    if (hasNext) {
        for (int t = tid; t < 1024; t += 256) WmL[t] = Wm_nx[t];
        if (tid < 32) bmL[tid] = bm_nx[tid];
    }
    if (tid < 32) { baL[tid] = ba[tid]; WgL[tid] = Wg[tid]; W1L[tid] = Wa1[tid]; bfL[tid] = bf[tid]; }
    if (tid == 0) { bgL = bg[0]; b1L = ba1[0]; }
    int s = tid >> 5, j = tid & 31;
    int c1 = j & 1, eo = j >> 1;    // 2 half-rows x 16 edge slots
    const uint4* m4 = (const uint4*)m_in;   // 2 uint4 per 32B fp8 row
    int nbase = blockIdx.x * NPB;
    int rep = blockIdx.x & (NREP - 1);
    float* Urep = U + (size_t)rep * GG * 32;
    float* Srep = S + (size_t)rep * GG;
    __syncthreads();
    int gcur = -1;
    float Uacc = 0.f, Sacc = 0.f;
    // zL/xnL rows private per 32-lane group -> wave-synchronous LDS, no barriers.
    for (int sub = 0; sub < NPB / 8; ++sub) {
        int n = nbase + sub * 8 + s;
        bool valid = n < N;
        int gb = gcur;
        if (valid) {
            zL[s][j] = x[n * 32 + j];
            gb = batch[n];
            zL[s][32 + j] = xg[gb * 32 + j];
        }
        if (valid && gb != gcur) {
            if (gcur >= 0) {
                atomicAdd(&Urep[gcur * 32 + j], Uacc);
                if (j == 0) atomicAdd(&Srep[gcur], Sacc);
            }
            gcur = gb; Uacc = 0.f; Sacc = 0.f;
        }
        unsigned st = 0, en = 0;
        if (valid) { st = indptr[n]; en = indptr[n + 1]; }
        float a[16];
#pragma unroll
        for (int t = 0; t < 16; ++t) a[t] = -INFINITY;
        if (en > st) {
            unsigned last = en - 1;
            for (unsigned base = st; base < en; base += 16) {
                unsigned e = min(base + eo, last);
                unsigned sA = ssrc[e];
                uint4 v = m4[sA * 2 + c1];
                float f0[4], f1[4], f2[4], f3[4];
                fp8unpk(v.x, f0); fp8unpk(v.y, f1);
                fp8unpk(v.z, f2); fp8unpk(v.w, f3);
#pragma unroll
                for (int t = 0; t < 4; ++t) {
                    a[t]      = fmaxf(a[t],      f0[t]);
                    a[4 + t]  = fmaxf(a[4 + t],  f1[t]);
                    a[8 + t]  = fmaxf(a[8 + t],  f2[t]);
                    a[12 + t] = fmaxf(a[12 + t], f3[t]);
                }
            }
        }
        // reduce over the 16 edge slots (lane bits 1..4)
#pragma unroll
        for (int off = 2; off <= 16; off <<= 1) {
#pragma unroll
            for (int t = 0; t < 16; ++t) a[t] = fmaxf(a[t], __shfl_xor(a[t], off));
        }
        if (valid && eo == 0) {
            bool empty = (st == en);
#pragma unroll
            for (int t = 0; t < 16; ++t)
                zL[s][64 + c1 * 16 + t] = empty ? 0.f : a[t];
        }
        if (valid) {
            float acc = baL[j];
#pragma unroll
            for (int k = 0; k < 96; ++k) acc += zL[s][k] * WL[k * 32 + j];
            float xn = lrelu(acc) + zL[s][j];
            x[n * 32 + j] = xn;
            xnL[s][j] = xn;
            float lv = xn * WgL[j];
            float l1 = xn * W1L[j];
#pragma unroll
            for (int off = 16; off; off >>= 1) { lv += __shfl_xor(lv, off); l1 += __shfl_xor(l1, off); }
            if (j == 0) la1[n] = l1 + b1L;
            float e = __expf(lv + bgL);
            float f = bfL[j];
#pragma unroll
            for (int k = 0; k < 32; ++k) f += xnL[s][k] * WfL[k * 32 + j];
            Uacc += e * lrelu(f);
            Sacc += e;
            if (hasNext) {
                float a2 = bmL[j];
#pragma unroll
                for (int k = 0; k < 32; ++k) a2 += xnL[s][k] * WmL[k * 32 + j];
                m_out[n * 32 + j] = fp8enc(lrelu(a2));
            }
        }
    }
    if (gcur >= 0) {
        atomicAdd(&Urep[gcur * 32 + j], Uacc);
        if (j == 0) atomicAdd(&Srep[gcur], Sacc);
    }
}

// ---------------- reduce replicas + xg transform + residual + reset ----------------
__global__ void k_gupd(float* __restrict__ U, float* __restrict__ S,
                       const float* __restrict__ xg_in,
                       const float* __restrict__ Wt, const float* __restrict__ bt,
                       float* __restrict__ xg_out) {
    __shared__ float pl[8][32];
    int idx = blockIdx.x * 256 + threadIdx.x;  // 0..GG*32-1
    int g = idx >> 5, j = idx & 31;
    int lg = threadIdx.x >> 5;
    float usum = 0.f, ssum = 0.f;
#pragma unroll 4
    for (int r = 0; r < NREP; ++r) {
        usum += U[(size_t)r * GG * 32 + idx];
        U[(size_t)r * GG * 32 + idx] = 0.f;   // reset for next step
        ssum += S[r * GG + g];
    }
    if (j == 0) {
        for (int r = 0; r < NREP; ++r) S[r * GG + g] = 0.f;
    }
    float inv = (ssum > 0.f) ? 1.f / ssum : 0.f;
    pl[lg][j] = usum * inv;
    __syncthreads();
    float acc = bt[j];
#pragma unroll
    for (int k = 0; k < 32; ++k) acc += pl[lg][k] * Wt[k * 32 + j];
#pragma unroll
    for (int k = 0; k < 32; ++k) acc += xg_in[g * 32 + k] * Wt[(32 + k) * 32 + j];
    xg_out[idx] = lrelu(acc) + xg_in[idx];
}

// ---------------- final: a1 softmax + value + a0 probs ----------------
__global__ void k_final(const float* __restrict__ logits, const int* __restrict__ goff,
                        const float* __restrict__ xg,
                        const void* __restrict__ Wv, const void* __restrict__ bv,
                        const void* __restrict__ Wa0, const void* __restrict__ ba0,
                        void* __restrict__ out, int N, const int* __restrict__ dtf) {
    __shared__ float red[256];
    int isf = *dtf;
    int g = blockIdx.x, tid = threadIdx.x;
    int s0 = goff[g], s1 = goff[g + 1];
    float lm = -INFINITY;
    for (int n = s0 + tid; n < s1; n += 256) lm = fmaxf(lm, logits[n]);
    red[tid] = lm;
    __syncthreads();
    for (int off = 128; off; off >>= 1) {
        if (tid < off) red[tid] = fmaxf(red[tid], red[tid + off]);
        __syncthreads();
    }
    float gmax = red[0];
    __syncthreads();
    float ls = 0.f;
    for (int n = s0 + tid; n < s1; n += 256) ls += expf(logits[n] - gmax);
    red[tid] = ls;
    __syncthreads();
    for (int off = 128; off; off >>= 1) {
        if (tid < off) red[tid] += red[tid + off];
        __syncthreads();
    }
    float inv = (red[0] > 0.f) ? 1.f / red[0] : 0.f;
    __syncthreads();
    for (int n = s0 + tid; n < s1; n += 256)
        stf(out, 384 + n, expf(logits[n] - gmax) * inv, isf);
    if (tid == 0) {
        float acc = ldf(bv, 0, isf);
        for (int k = 0; k < 32; ++k) acc += xg[g * 32 + k] * ldf(Wv, k, isf);
        stf(out, g, acc, isf);
        float l0 = ldf(ba0, 0, isf), l1 = ldf(ba0, 1, isf);
        for (int k = 0; k < 32; ++k) {
            float xv = xg[g * 32 + k];
            l0 += xv * ldf(Wa0, k * 2, isf);
            l1 += xv * ldf(Wa0, k * 2 + 1, isf);
        }
        float mm = fmaxf(l0, l1);
        float e0 = expf(l0 - mm), e1 = expf(l1 - mm);
        float si = 1.f / (e0 + e1);
        stf(out, 128 + 2 * g, e0 * si, isf);
        stf(out, 128 + 2 * g + 1, e1 * si, isf);
    }
}

extern "C" void kernel_launch(void* const* d_in, const int* in_sizes, int n_in,
                              void* d_out, int out_size, void* d_ws, size_t ws_size,
                              hipStream_t stream) {
    const void* nf      = d_in[0];
    const int*  eidx    = (const int*)d_in[1];
    const int*  batch   = (const int*)d_in[2];
    const void* W_embed = d_in[4];
    const void* b_embed = d_in[5];
    const void* Wm      = d_in[6];
    const void* bm      = d_in[7];
    const void* Wa      = d_in[8];
    const void* ba      = d_in[9];
    const void* Wgate   = d_in[10];
    const void* bgate   = d_in[11];
    const void* Wfeat   = d_in[12];
    const void* bfeat   = d_in[13];
    const void* Wt      = d_in[14];
    const void* bt      = d_in[15];
    const void* W_v     = d_in[16];
    const void* b_v     = d_in[17];
    const void* W_a0    = d_in[18];
    const void* b_a0    = d_in[19];
    const void* W_a1    = d_in[20];
    const void* b_a1    = d_in[21];

    const int N = in_sizes[0];
    const int E = in_sizes[1] / 2;
    const int nWm = in_sizes[6];  // 3*32*32 = 3072
    const int* src = eidx;
    const int* dst = eidx + E;
    const int B = (N + 255) >> 8;

    char* ws = (char*)d_ws;
    size_t off = 0;
    auto alloc = [&](size_t bytes) -> char* {
        char* p = ws + off;
        off = (off + bytes + 255) & ~(size_t)255;
        return p;
    };
    float*          x      = (float*)alloc((size_t)N * 32 * 4);
    // packed (E*8 B) aliases m_a+m_b (2 * N*32 B fp8): packed dead after k_csr.
    size_t mBytes  = (size_t)N * 32;
    size_t pkBytes = (size_t)E * 8;
    size_t rBytes  = (2 * mBytes > pkBytes) ? 2 * mBytes : pkBytes;
    char*  mRegion = alloc(rBytes);
    unsigned long long* packed = (unsigned long long*)mRegion;
    unsigned char*      m_a    = (unsigned char*)mRegion;
    unsigned char*      m_b    = (unsigned char*)(mRegion + mBytes);
    float*          la1    = (float*)alloc((size_t)N * 4);
    unsigned*       indptr = (unsigned*)alloc((size_t)(N + 1) * 4);
    unsigned*       cursor = (unsigned*)alloc((size_t)N * 4);
    unsigned*       ssrc   = (unsigned*)alloc((size_t)(E + 16) * 4);
    const int nb = (N + 255) / 256;
    unsigned*       bsum   = (unsigned*)alloc((size_t)nb * 4);
    unsigned*       boff   = (unsigned*)alloc((size_t)nb * 4);
    unsigned*       bcnt   = (unsigned*)alloc((size_t)(B + 1) * 4);
    unsigned*       bbase  = (unsigned*)alloc((size_t)(B + 1) * 4);
    unsigned*       bcur   = (unsigned*)alloc((size_t)(B + 1) * 4);
    int*            goff   = (int*)alloc((size_t)(GG + 1) * 4);
    float*          xg_a   = (float*)alloc((size_t)GG * 32 * 4);
    float*          xg_b   = (float*)alloc((size_t)GG * 32 * 4);
    float*          U      = (float*)alloc((size_t)NREP * GG * 32 * 4);
    float*          S      = (float*)alloc((size_t)NREP * GG * 4);
    int*            dtf    = (int*)alloc(256);
    float*          wcat   = (float*)alloc((size_t)WCAT_N * 4);

    const int nB_n  = (N + 255) / 256;
    const int nB_e  = (E + 255) / 256;
    const int nB_n8 = (N + 7) / 8;
    const int nB_st = (N + NPB - 1) / NPB;
    const int nB_ch = (E + CHUNK - 1) / CHUNK;

    hipMemsetAsync(xg_a, 0, (size_t)GG * 32 * 4, stream);
    hipMemsetAsync(bcnt, 0, (size_t)(B + 1) * 4, stream);
    hipMemsetAsync(U, 0, (size_t)NREP * GG * 32 * 4, stream);
    hipMemsetAsync(S, 0, (size_t)NREP * GG * 4, stream);

    k_detect<<<1, 256, 0, stream>>>((const unsigned short*)Wm, nWm, dtf);

    CvtArgs ca;
    const void* ps[12] = {Wm, bm, Wa, ba, Wgate, bgate, Wfeat, bfeat, Wt, bt, W_a1, b_a1};
    const int  offs[12] = {OFF_Wm, OFF_bm, OFF_Wa, OFF_ba, OFF_Wg, OFF_bg,
                           OFF_Wf, OFF_bf, OFF_Wt, OFF_bt, OFF_Wa1, OFF_ba1};
    const int  ns[12]  = {3072, 96, 9216, 96, 96, 3, 3072, 96, 6144, 96, 32, 1};
    for (int i = 0; i < 12; ++i) { ca.p[i] = ps[i]; ca.off[i] = offs[i]; ca.n[i] = ns[i]; }
    k_cvt_all<<<dim3(36, 12), 256, 0, stream>>>(ca, wcat, dtf);

    k_graph_off<<<nB_n, 256, 0, stream>>>(batch, goff, N);

    // CSR build first (packed aliases m buffers; m written after)
    if (B <= 2048) {
        k_bhist<<<nB_ch, 256, 0, stream>>>(dst, bcnt, E, B);
        k_bscan<<<1, 256, 0, stream>>>(bcnt, bbase, bcur, B, E);
        k_binA<<<nB_ch, 256, 0, stream>>>(src, dst, bcur, packed, E, B);
        k_csr<<<B, 256, 0, stream>>>(packed, bbase, indptr, ssrc, N, E);
    } else {
        hipMemsetAsync(cursor, 0, (size_t)N * 4, stream);
        k_hist<<<nB_e, 256, 0, stream>>>(dst, cursor, E);
        k_scan1<<<nb, 256, 0, stream>>>(cursor, indptr, bsum, N);
        k_scan2<<<1, 256, 0, stream>>>(bsum, boff, nb);
        k_scan3<<<nB_n, 256, 0, stream>>>(indptr, boff, cursor, N, E);
        k_scatter<<<nB_e, 256, 0, stream>>>(src, dst, cursor, ssrc, E);
    }

    // embed + step-0 message (fp8 node-major m)
    k_embed_msg<<<nB_n8, 256, 0, stream>>>(nf, W_embed, b_embed,
                                           wcat + OFF_Wm, wcat + OFF_bm, x, m_a, N, dtf);

    float* xg_cur = xg_a;
    float* xg_nxt = xg_b;
    unsigned char* m_cur = m_a;
    unsigned char* m_nxt = m_b;
    for (int i = 0; i < 3; ++i) {
        int hasNext = (i < 2) ? 1 : 0;
        k_step<<<nB_st, 256, 0, stream>>>(x, m_cur, m_nxt, xg_cur, batch, indptr, ssrc,
                                          wcat + OFF_Wa + i * 3072, wcat + OFF_ba + i * 32,
                                          wcat + OFF_Wg + i * 32, wcat + OFF_bg + i,
                                          wcat + OFF_Wa1, wcat + OFF_ba1,
                                          wcat + OFF_Wf + i * 1024, wcat + OFF_bf + i * 32,
                                          wcat + OFF_Wm + (i + 1) * 1024,
                                          wcat + OFF_bm + (i + 1) * 32,
                                          la1, U, S, N, hasNext);
        k_gupd<<<(GG * 32 + 255) / 256, 256, 0, stream>>>(U, S, xg_cur,
                                                          wcat + OFF_Wt + i * 2048,
                                                          wcat + OFF_bt + i * 32, xg_nxt);
        float* tmp = xg_cur; xg_cur = xg_nxt; xg_nxt = tmp;
        unsigned char* tm = m_cur; m_cur = m_nxt; m_nxt = tm;
    }

    k_final<<<GG, 256, 0, stream>>>(la1, goff, xg_cur, W_v, b_v, W_a0, b_a0,
                                    d_out, N, dtf);
}

// Round 13
// 717.437 us; speedup vs baseline: 1.1967x; 1.1967x over previous
//
#include <hip/hip_runtime.h>
#include <hip/hip_bf16.h>

#define GG 128
#define SLOPE 0.01f
#define CHUNK 8192
#define NPB 64   // nodes per block in k_step
#define NREP 64  // accumulator replicas (atomic contention striping)

// wcat element offsets (f32 staged weights)
#define OFF_Wm   0
#define OFF_bm   3072
#define OFF_Wa   3168
#define OFF_ba   12384
#define OFF_Wg   12480
#define OFF_bg   12576
#define OFF_Wf   12592
#define OFF_bf   15664
#define OFF_Wt   15760
#define OFF_bt   21904
#define OFF_Wa1  22000
#define OFF_ba1  22032
#define WCAT_N   22048

__device__ __forceinline__ float lrelu(float v) { return v > 0.f ? v : SLOPE * v; }
__device__ __forceinline__ float b2f(__hip_bfloat16 v) { return __bfloat162float(v); }

__device__ __forceinline__ float ldf(const void* p, int i, int isf) {
    if (isf) return ((const float*)p)[i];
    return __bfloat162float(((const __hip_bfloat16*)p)[i]);
}
__device__ __forceinline__ void stf(void* p, int i, float v, int isf) {
    if (isf) ((float*)p)[i] = v;
    else ((__hip_bfloat16*)p)[i] = __float2bfloat16(v);
}

// bf16-pair unpack from u32 (bit ops only)
__device__ __forceinline__ float bfLo(unsigned u) { return __uint_as_float(u << 16); }
__device__ __forceinline__ float bfHi(unsigned u) { return __uint_as_float(u & 0xFFFF0000u); }

// ---------------- dtype detection ----------------
__global__ void k_detect(const unsigned short* __restrict__ w, int n, int* __restrict__ flag) {
    __shared__ int bad;
    if (threadIdx.x == 0) bad = 0;
    __syncthreads();
    for (int t = threadIdx.x; t < n; t += 256) {
        unsigned short u = w[t];
        int e = (u >> 7) & 0xFF;
        if (e >= 141) bad = 1;  // benign same-value race
    }
    __syncthreads();
    if (threadIdx.x == 0) { flag[0] = bad; flag[32] = 1; }
}

// ---------------- one-shot weight staging to f32 ----------------
struct CvtArgs {
    const void* p[12];
    int off[12];
    int n[12];
};
__global__ void k_cvt_all(CvtArgs a, float* __restrict__ dst, const int* __restrict__ dtf) {
    int isf = *dtf;
    int seg = blockIdx.y;
    int i = blockIdx.x * 256 + threadIdx.x;
    if (i < a.n[seg]) dst[a.off[seg] + i] = ldf(a.p[seg], i, isf);
}

// ---------------- embed + step-0 message (fused; m node-major) ----------------
__global__ void k_embed_msg(const void* __restrict__ nf, const void* __restrict__ We,
                            const void* __restrict__ be,
                            const float* __restrict__ Wm0, const float* __restrict__ bm0,
                            float* __restrict__ x, __hip_bfloat16* __restrict__ m, int N,
                            const int* __restrict__ dtf) {
    __shared__ float WL[1024];
    __shared__ float WeL[32], beL[32], bmL[32];
    __shared__ float xs[8][32];
    int isf = *dtf;
    int tid = threadIdx.x;
    for (int t = tid; t < 1024; t += 256) WL[t] = Wm0[t];
    if (tid < 32) { WeL[tid] = ldf(We, tid, isf); beL[tid] = ldf(be, tid, isf); bmL[tid] = bm0[tid]; }
    int s = tid >> 5, j = tid & 31;
    int n = blockIdx.x * 8 + s;
    __syncthreads();
    float xv = 0.f;
    if (n < N) {
        xv = lrelu(ldf(nf, n, isf) * WeL[j] + beL[j]);
        x[n * 32 + j] = xv;
        xs[s][j] = xv;
    }
    __syncthreads();
    if (n >= N) return;
    float acc = bmL[j];
#pragma unroll
    for (int k = 0; k < 32; ++k) acc += xs[s][k] * WL[k * 32 + j];
    m[n * 32 + j] = __float2bfloat16(lrelu(acc));
}

// ---------------- graph offsets from sorted batch ----------------
__global__ void k_graph_off(const int* __restrict__ batch, int* __restrict__ goff, int N) {
    int n = blockIdx.x * 256 + threadIdx.x;
    if (n >= N) return;
    int bn = batch[n];
    if (n == 0) {
        for (int g = 0; g <= bn; ++g) goff[g] = 0;
    } else {
        int bp = batch[n - 1];
        for (int g = bp + 1; g <= bn; ++g) goff[g] = n;
    }
    if (n == N - 1) {
        for (int g = bn + 1; g <= GG; ++g) goff[g] = N;
    }
}

// ---------------- fallback CSR build (B > 2048 only) ----------------
__global__ void k_hist(const int* __restrict__ dst, unsigned* __restrict__ deg, int E) {
    int e = blockIdx.x * 256 + threadIdx.x;
    if (e >= E) return;
    atomicAdd(&deg[dst[e]], 1u);
}
__global__ void k_scan1(const unsigned* __restrict__ deg, unsigned* __restrict__ excl,
                        unsigned* __restrict__ bsum, int N) {
    __shared__ unsigned s[256];
    int i = blockIdx.x * 256 + threadIdx.x;
    unsigned v = (i < N) ? deg[i] : 0u;
    s[threadIdx.x] = v;
    __syncthreads();
    for (int off = 1; off < 256; off <<= 1) {
        unsigned t = (threadIdx.x >= (unsigned)off) ? s[threadIdx.x - off] : 0u;
        __syncthreads();
        s[threadIdx.x] += t;
        __syncthreads();
    }
    if (i < N) excl[i] = s[threadIdx.x] - v;
    if (threadIdx.x == 255) bsum[blockIdx.x] = s[255];
}
__global__ void k_scan2(const unsigned* __restrict__ bsum, unsigned* __restrict__ boff, int nb) {
    __shared__ unsigned s[256];
    __shared__ unsigned carry;
    if (threadIdx.x == 0) carry = 0u;
    __syncthreads();
    for (int base = 0; base < nb; base += 256) {
        int i = base + threadIdx.x;
        unsigned v = (i < nb) ? bsum[i] : 0u;
        s[threadIdx.x] = v;
        __syncthreads();
        for (int off = 1; off < 256; off <<= 1) {
            unsigned t = (threadIdx.x >= (unsigned)off) ? s[threadIdx.x - off] : 0u;
            __syncthreads();
            s[threadIdx.x] += t;
            __syncthreads();
        }
        if (i < nb) boff[i] = carry + s[threadIdx.x] - v;
        __syncthreads();
        if (threadIdx.x == 0) carry += s[255];
        __syncthreads();
    }
}
__global__ void k_scan3(unsigned* __restrict__ indptr, const unsigned* __restrict__ boff,
                        unsigned* __restrict__ cursor, int N, int E) {
    int i = blockIdx.x * 256 + threadIdx.x;
    if (i >= N) return;
    unsigned v = indptr[i] + boff[i >> 8];
    indptr[i] = v;
    cursor[i] = v;
    if (i == 0) indptr[N] = (unsigned)E;
}
__global__ void k_scatter(const int* __restrict__ src, const int* __restrict__ dst,
                          unsigned* __restrict__ cursor, unsigned* __restrict__ ssrc, int E) {
    int e = blockIdx.x * 256 + threadIdx.x;
    if (e >= E) return;
    unsigned pos = atomicAdd(&cursor[dst[e]], 1u);
    ssrc[pos] = (unsigned)src[e];
}

// ---------------- bucketed CSR build ----------------
__global__ void k_bhist(const int* __restrict__ dst, unsigned* __restrict__ bcnt, int E, int B) {
    __shared__ unsigned h[2048];
    for (int t = threadIdx.x; t < B; t += 256) h[t] = 0;
    __syncthreads();
    int start = blockIdx.x * CHUNK, end = min(E, start + CHUNK);
    for (int e = start + threadIdx.x; e < end; e += 256)
        atomicAdd(&h[dst[e] >> 8], 1u);
    __syncthreads();
    for (int t = threadIdx.x; t < B; t += 256)
        if (h[t]) atomicAdd(&bcnt[t], h[t]);
}

__global__ void k_bscan(const unsigned* __restrict__ bcnt, unsigned* __restrict__ bbase,
                        unsigned* __restrict__ bcur, int B, int E) {
    __shared__ unsigned s[256];
    __shared__ unsigned carry;
    if (threadIdx.x == 0) carry = 0u;
    __syncthreads();
    for (int base = 0; base < B; base += 256) {
        int i = base + threadIdx.x;
        unsigned v = (i < B) ? bcnt[i] : 0u;
        s[threadIdx.x] = v;
        __syncthreads();
        for (int off = 1; off < 256; off <<= 1) {
            unsigned t = (threadIdx.x >= (unsigned)off) ? s[threadIdx.x - off] : 0u;
            __syncthreads();
            s[threadIdx.x] += t;
            __syncthreads();
        }
        if (i < B) {
            unsigned ex = carry + s[threadIdx.x] - v;
            bbase[i] = ex;
            bcur[i] = ex;
        }
        __syncthreads();
        if (threadIdx.x == 0) carry += s[255];
        __syncthreads();
    }
    if (threadIdx.x == 0) bbase[B] = (unsigned)E;
}

__global__ void k_binA(const int* __restrict__ src, const int* __restrict__ dst,
                       unsigned* __restrict__ bcur, unsigned long long* __restrict__ packed,
                       int E, int B) {
    __shared__ unsigned h[2048];
    __shared__ unsigned pos[2048];
    for (int t = threadIdx.x; t < B; t += 256) h[t] = 0;
    __syncthreads();
    int start = blockIdx.x * CHUNK, end = min(E, start + CHUNK);
    for (int e = start + threadIdx.x; e < end; e += 256)
        atomicAdd(&h[dst[e] >> 8], 1u);
    __syncthreads();
    for (int t = threadIdx.x; t < B; t += 256)
        pos[t] = h[t] ? atomicAdd(&bcur[t], h[t]) : 0u;
    __syncthreads();
    for (int e = start + threadIdx.x; e < end; e += 256) {
        int d = dst[e];
        unsigned p = atomicAdd(&pos[d >> 8], 1u);
        packed[p] = ((unsigned long long)(unsigned)d << 32) | (unsigned)src[e];
    }
}

// per-bucket: LDS degree count + scan -> indptr, then bucket-local scatter
__global__ void k_csr(const unsigned long long* __restrict__ packed,
                      const unsigned* __restrict__ bbase,
                      unsigned* __restrict__ indptr,
                      unsigned* __restrict__ ssrc, int N, int E) {
    __shared__ unsigned deg[256];
    __shared__ unsigned scn[256];
    __shared__ unsigned cur[256];
    int g = blockIdx.x, tid = threadIdx.x;
    int n0 = g << 8;
    int cnt = min(256, N - n0);
    deg[tid] = 0;
    __syncthreads();
    unsigned e0 = bbase[g], e1 = bbase[g + 1];
    for (unsigned e = e0 + tid; e < e1; e += 256) {
        int d = (int)(packed[e] >> 32);
        atomicAdd(&deg[d - n0], 1u);
    }
    __syncthreads();
    unsigned v = deg[tid];
    scn[tid] = v;
    __syncthreads();
    for (int off = 1; off < 256; off <<= 1) {
        unsigned t = (tid >= off) ? scn[tid - off] : 0u;
        __syncthreads();
        scn[tid] += t;
        __syncthreads();
    }
    unsigned start = e0 + scn[tid] - v;
    if (tid < cnt) { indptr[n0 + tid] = start; cur[tid] = start; }
    if (g == (int)gridDim.x - 1 && tid == 0) indptr[N] = (unsigned)E;
    __syncthreads();
    for (unsigned e = e0 + tid; e < e1; e += 256) {
        unsigned long long pk = packed[e];
        int d = (int)(pk >> 32);
        unsigned p = atomicAdd(&cur[d - n0], 1u);
        ssrc[p] = (unsigned)pk;
    }
}

// ---------------- fused step (round-7 gather + GlobalAttention, striped accumulators) --------
// Per node: gather-max -> f_agg -> gate/a1 logits -> feat=lrelu(xn@Wf+bf),
// e=exp(gate_logit) (no max-sub: logits O(0.3), f32-safe). Per-graph U += e*feat,
// S += e accumulated in registers, flushed to replica blockIdx&63 (contention-free).
__global__ void k_step(float* __restrict__ x, const __hip_bfloat16* __restrict__ m_in,
                       __hip_bfloat16* __restrict__ m_out,
                       const float* __restrict__ xg, const int* __restrict__ batch,
                       const unsigned* __restrict__ indptr, const unsigned* __restrict__ ssrc,
                       const float* __restrict__ Wa, const float* __restrict__ ba,
                       const float* __restrict__ Wg, const float* __restrict__ bg,
                       const float* __restrict__ Wa1, const float* __restrict__ ba1,
                       const float* __restrict__ Wf, const float* __restrict__ bf,
                       const float* __restrict__ Wm_nx, const float* __restrict__ bm_nx,
                       float* __restrict__ la1, float* __restrict__ U, float* __restrict__ S,
                       int N, int hasNext) {
    __shared__ float WL[3072];
    __shared__ float WmL[1024];
    __shared__ float WfL[1024];
    __shared__ float zL[8][96];
    __shared__ float xnL[8][32];
    __shared__ float baL[32], WgL[32], W1L[32], bmL[32], bfL[32];
    __shared__ float bgL, b1L;
    int tid = threadIdx.x;
    for (int t = tid; t < 3072; t += 256) WL[t] = Wa[t];
    for (int t = tid; t < 1024; t += 256) WfL[t] = Wf[t];
    if (hasNext) {
        for (int t = tid; t < 1024; t += 256) WmL[t] = Wm_nx[t];
        if (tid < 32) bmL[tid] = bm_nx[tid];
    }
    if (tid < 32) { baL[tid] = ba[tid]; WgL[tid] = Wg[tid]; W1L[tid] = Wa1[tid]; bfL[tid] = bf[tid]; }
    if (tid == 0) { bgL = bg[0]; b1L = ba1[0]; }
    int s = tid >> 5, j = tid & 31;
    int c = j & 3, eo = j >> 2;
    const uint4* m4 = (const uint4*)m_in;
    int nbase = blockIdx.x * NPB;
    int rep = blockIdx.x & (NREP - 1);
    float* Urep = U + (size_t)rep * GG * 32;
    float* Srep = S + (size_t)rep * GG;
    __syncthreads();
    int gcur = -1;
    float Uacc = 0.f, Sacc = 0.f;
    // zL/xnL rows private per 32-lane group -> wave-synchronous LDS, no barriers.
    for (int sub = 0; sub < NPB / 8; ++sub) {
        int n = nbase + sub * 8 + s;
        bool valid = n < N;
        int gb = gcur;
        if (valid) {
            zL[s][j] = x[n * 32 + j];
            gb = batch[n];
            zL[s][32 + j] = xg[gb * 32 + j];
        }
        if (valid && gb != gcur) {
            if (gcur >= 0) {
                atomicAdd(&Urep[gcur * 32 + j], Uacc);
                if (j == 0) atomicAdd(&Srep[gcur], Sacc);
            }
            gcur = gb; Uacc = 0.f; Sacc = 0.f;
        }
        unsigned st = 0, en = 0;
        if (valid) { st = indptr[n]; en = indptr[n + 1]; }
        float a[8];
#pragma unroll
        for (int t = 0; t < 8; ++t) a[t] = -INFINITY;
        if (en > st) {
            unsigned last = en - 1;
            for (unsigned base = st; base < en; base += 16) {
                unsigned eA = min(base + eo, last);
                unsigned eB = min(base + 8 + eo, last);
                unsigned sA = ssrc[eA];
                unsigned sB = ssrc[eB];
                uint4 vA = m4[sA * 4 + c];
                uint4 vB = m4[sB * 4 + c];
                a[0] = fmaxf(a[0], fmaxf(bfLo(vA.x), bfLo(vB.x)));
                a[1] = fmaxf(a[1], fmaxf(bfHi(vA.x), bfHi(vB.x)));
                a[2] = fmaxf(a[2], fmaxf(bfLo(vA.y), bfLo(vB.y)));
                a[3] = fmaxf(a[3], fmaxf(bfHi(vA.y), bfHi(vB.y)));
                a[4] = fmaxf(a[4], fmaxf(bfLo(vA.z), bfLo(vB.z)));
                a[5] = fmaxf(a[5], fmaxf(bfHi(vA.z), bfHi(vB.z)));
                a[6] = fmaxf(a[6], fmaxf(bfLo(vA.w), bfLo(vB.w)));
                a[7] = fmaxf(a[7], fmaxf(bfHi(vA.w), bfHi(vB.w)));
            }
        }
#pragma unroll
        for (int t = 0; t < 8; ++t) {
            a[t] = fmaxf(a[t], __shfl_xor(a[t], 4));
            a[t] = fmaxf(a[t], __shfl_xor(a[t], 8));
            a[t] = fmaxf(a[t], __shfl_xor(a[t], 16));
        }
        if (valid && eo == 0) {
            bool empty = (st == en);
#pragma unroll
            for (int t = 0; t < 8; ++t)
                zL[s][64 + c * 8 + t] = empty ? 0.f : a[t];
        }
        if (valid) {
            float acc = baL[j];
#pragma unroll
            for (int k = 0; k < 96; ++k) acc += zL[s][k] * WL[k * 32 + j];
            float xn = lrelu(acc) + zL[s][j];
            x[n * 32 + j] = xn;
            xnL[s][j] = xn;
            float lv = xn * WgL[j];
            float l1 = xn * W1L[j];
#pragma unroll
            for (int off = 16; off; off >>= 1) { lv += __shfl_xor(lv, off); l1 += __shfl_xor(l1, off); }
            if (j == 0) la1[n] = l1 + b1L;
            float e = __expf(lv + bgL);
            float f = bfL[j];
#pragma unroll
            for (int k = 0; k < 32; ++k) f += xnL[s][k] * WfL[k * 32 + j];
            Uacc += e * lrelu(f);
            Sacc += e;
            if (hasNext) {
                float a2 = bmL[j];
#pragma unroll
                for (int k = 0; k < 32; ++k) a2 += xnL[s][k] * WmL[k * 32 + j];
                m_out[n * 32 + j] = __float2bfloat16(lrelu(a2));
            }
        }
    }
    if (gcur >= 0) {
        atomicAdd(&Urep[gcur * 32 + j], Uacc);
        if (j == 0) atomicAdd(&Srep[gcur], Sacc);
    }
}

// ---------------- reduce replicas + xg transform + residual + reset ----------------
__global__ void k_gupd(float* __restrict__ U, float* __restrict__ S,
                       const float* __restrict__ xg_in,
                       const float* __restrict__ Wt, const float* __restrict__ bt,
                       float* __restrict__ xg_out) {
    __shared__ float pl[8][32];
    int idx = blockIdx.x * 256 + threadIdx.x;  // 0..GG*32-1
    int g = idx >> 5, j = idx & 31;
    int lg = threadIdx.x >> 5;
    float usum = 0.f, ssum = 0.f;
#pragma unroll 4
    for (int r = 0; r < NREP; ++r) {
        usum += U[(size_t)r * GG * 32 + idx];
        U[(size_t)r * GG * 32 + idx] = 0.f;   // reset for next step
        ssum += S[r * GG + g];
    }
    if (j == 0) {
        for (int r = 0; r < NREP; ++r) S[r * GG + g] = 0.f;
    }
    float inv = (ssum > 0.f) ? 1.f / ssum : 0.f;
    pl[lg][j] = usum * inv;
    __syncthreads();
    float acc = bt[j];
#pragma unroll
    for (int k = 0; k < 32; ++k) acc += pl[lg][k] * Wt[k * 32 + j];
#pragma unroll
    for (int k = 0; k < 32; ++k) acc += xg_in[g * 32 + k] * Wt[(32 + k) * 32 + j];
    xg_out[idx] = lrelu(acc) + xg_in[idx];
}

// ---------------- final: a1 softmax + value + a0 probs ----------------
__global__ void k_final(const float* __restrict__ logits, const int* __restrict__ goff,
                        const float* __restrict__ xg,
                        const void* __restrict__ Wv, const void* __restrict__ bv,
                        const void* __restrict__ Wa0, const void* __restrict__ ba0,
                        void* __restrict__ out, int N, const int* __restrict__ dtf) {
    __shared__ float red[256];
    int isf = *dtf;
    int g = blockIdx.x, tid = threadIdx.x;
    int s0 = goff[g], s1 = goff[g + 1];
    float lm = -INFINITY;
    for (int n = s0 + tid; n < s1; n += 256) lm = fmaxf(lm, logits[n]);
    red[tid] = lm;
    __syncthreads();
    for (int off = 128; off; off >>= 1) {
        if (tid < off) red[tid] = fmaxf(red[tid], red[tid + off]);
        __syncthreads();
    }
    float gmax = red[0];
    __syncthreads();
    float ls = 0.f;
    for (int n = s0 + tid; n < s1; n += 256) ls += expf(logits[n] - gmax);
    red[tid] = ls;
    __syncthreads();
    for (int off = 128; off; off >>= 1) {
        if (tid < off) red[tid] += red[tid + off];
        __syncthreads();
    }
    float inv = (red[0] > 0.f) ? 1.f / red[0] : 0.f;
    __syncthreads();
    for (int n = s0 + tid; n < s1; n += 256)
        stf(out, 384 + n, expf(logits[n] - gmax) * inv, isf);
    if (tid == 0) {
        float acc = ldf(bv, 0, isf);
        for (int k = 0; k < 32; ++k) acc += xg[g * 32 + k] * ldf(Wv, k, isf);
        stf(out, g, acc, isf);
        float l0 = ldf(ba0, 0, isf), l1 = ldf(ba0, 1, isf);
        for (int k = 0; k < 32; ++k) {
            float xv = xg[g * 32 + k];
            l0 += xv * ldf(Wa0, k * 2, isf);
            l1 += xv * ldf(Wa0, k * 2 + 1, isf);
        }
        float mm = fmaxf(l0, l1);
        float e0 = expf(l0 - mm), e1 = expf(l1 - mm);
        float si = 1.f / (e0 + e1);
        stf(out, 128 + 2 * g, e0 * si, isf);
        stf(out, 128 + 2 * g + 1, e1 * si, isf);
    }
}

extern "C" void kernel_launch(void* const* d_in, const int* in_sizes, int n_in,
                              void* d_out, int out_size, void* d_ws, size_t ws_size,
                              hipStream_t stream) {
    const void* nf      = d_in[0];
    const int*  eidx    = (const int*)d_in[1];
    const int*  batch   = (const int*)d_in[2];
    const void* W_embed = d_in[4];
    const void* b_embed = d_in[5];
    const void* Wm      = d_in[6];
    const void* bm      = d_in[7];
    const void* Wa      = d_in[8];
    const void* ba      = d_in[9];
    const void* Wgate   = d_in[10];
    const void* bgate   = d_in[11];
    const void* Wfeat   = d_in[12];
    const void* bfeat   = d_in[13];
    const void* Wt      = d_in[14];
    const void* bt      = d_in[15];
    const void* W_v     = d_in[16];
    const void* b_v     = d_in[17];
    const void* W_a0    = d_in[18];
    const void* b_a0    = d_in[19];
    const void* W_a1    = d_in[20];
    const void* b_a1    = d_in[21];

    const int N = in_sizes[0];
    const int E = in_sizes[1] / 2;
    const int nWm = in_sizes[6];  // 3*32*32 = 3072
    const int* src = eidx;
    const int* dst = eidx + E;
    const int B = (N + 255) >> 8;

    char* ws = (char*)d_ws;
    size_t off = 0;
    auto alloc = [&](size_t bytes) -> char* {
        char* p = ws + off;
        off = (off + bytes + 255) & ~(size_t)255;
        return p;
    };
    float*          x      = (float*)alloc((size_t)N * 32 * 4);
    // packed (E*8 B) aliases m_a+m_b (2 * N*32*2 B): packed dead after k_csr.
    size_t mBytes  = (size_t)N * 32 * 2;
    size_t pkBytes = (size_t)E * 8;
    size_t rBytes  = (2 * mBytes > pkBytes) ? 2 * mBytes : pkBytes;
    char*  mRegion = alloc(rBytes);
    unsigned long long* packed = (unsigned long long*)mRegion;
    __hip_bfloat16*     m_a    = (__hip_bfloat16*)mRegion;
    __hip_bfloat16*     m_b    = (__hip_bfloat16*)(mRegion + mBytes);
    float*          la1    = (float*)alloc((size_t)N * 4);
    unsigned*       indptr = (unsigned*)alloc((size_t)(N + 1) * 4);
    unsigned*       cursor = (unsigned*)alloc((size_t)N * 4);
    unsigned*       ssrc   = (unsigned*)alloc((size_t)(E + 16) * 4);
    const int nb = (N + 255) / 256;
    unsigned*       bsum   = (unsigned*)alloc((size_t)nb * 4);
    unsigned*       boff   = (unsigned*)alloc((size_t)nb * 4);
    unsigned*       bcnt   = (unsigned*)alloc((size_t)(B + 1) * 4);
    unsigned*       bbase  = (unsigned*)alloc((size_t)(B + 1) * 4);
    unsigned*       bcur   = (unsigned*)alloc((size_t)(B + 1) * 4);
    int*            goff   = (int*)alloc((size_t)(GG + 1) * 4);
    float*          xg_a   = (float*)alloc((size_t)GG * 32 * 4);
    float*          xg_b   = (float*)alloc((size_t)GG * 32 * 4);
    float*          U      = (float*)alloc((size_t)NREP * GG * 32 * 4);
    float*          S      = (float*)alloc((size_t)NREP * GG * 4);
    int*            dtf    = (int*)alloc(256);
    float*          wcat   = (float*)alloc((size_t)WCAT_N * 4);

    const int nB_n  = (N + 255) / 256;
    const int nB_e  = (E + 255) / 256;
    const int nB_n8 = (N + 7) / 8;
    const int nB_st = (N + NPB - 1) / NPB;
    const int nB_ch = (E + CHUNK - 1) / CHUNK;

    hipMemsetAsync(xg_a, 0, (size_t)GG * 32 * 4, stream);
    hipMemsetAsync(bcnt, 0, (size_t)(B + 1) * 4, stream);
    hipMemsetAsync(U, 0, (size_t)NREP * GG * 32 * 4, stream);
    hipMemsetAsync(S, 0, (size_t)NREP * GG * 4, stream);

    k_detect<<<1, 256, 0, stream>>>((const unsigned short*)Wm, nWm, dtf);

    CvtArgs ca;
    const void* ps[12] = {Wm, bm, Wa, ba, Wgate, bgate, Wfeat, bfeat, Wt, bt, W_a1, b_a1};
    const int  offs[12] = {OFF_Wm, OFF_bm, OFF_Wa, OFF_ba, OFF_Wg, OFF_bg,
                           OFF_Wf, OFF_bf, OFF_Wt, OFF_bt, OFF_Wa1, OFF_ba1};
    const int  ns[12]  = {3072, 96, 9216, 96, 96, 3, 3072, 96, 6144, 96, 32, 1};
    for (int i = 0; i < 12; ++i) { ca.p[i] = ps[i]; ca.off[i] = offs[i]; ca.n[i] = ns[i]; }
    k_cvt_all<<<dim3(36, 12), 256, 0, stream>>>(ca, wcat, dtf);

    k_graph_off<<<nB_n, 256, 0, stream>>>(batch, goff, N);

    // CSR build first (packed aliases m buffers; m written after)
    if (B <= 2048) {
        k_bhist<<<nB_ch, 256, 0, stream>>>(dst, bcnt, E, B);
        k_bscan<<<1, 256, 0, stream>>>(bcnt, bbase, bcur, B, E);
        k_binA<<<nB_ch, 256, 0, stream>>>(src, dst, bcur, packed, E, B);
        k_csr<<<B, 256, 0, stream>>>(packed, bbase, indptr, ssrc, N, E);
    } else {
        hipMemsetAsync(cursor, 0, (size_t)N * 4, stream);
        k_hist<<<nB_e, 256, 0, stream>>>(dst, cursor, E);
        k_scan1<<<nb, 256, 0, stream>>>(cursor, indptr, bsum, N);
        k_scan2<<<1, 256, 0, stream>>>(bsum, boff, nb);
        k_scan3<<<nB_n, 256, 0, stream>>>(indptr, boff, cursor, N, E);
        k_scatter<<<nB_e, 256, 0, stream>>>(src, dst, cursor, ssrc, E);
    }

    // embed + step-0 message (node-major m)
    k_embed_msg<<<nB_n8, 256, 0, stream>>>(nf, W_embed, b_embed,
                                           wcat + OFF_Wm, wcat + OFF_bm, x, m_a, N, dtf);

    float* xg_cur = xg_a;
    float* xg_nxt = xg_b;
    __hip_bfloat16* m_cur = m_a;
    __hip_bfloat16* m_nxt = m_b;
    for (int i = 0; i < 3; ++i) {
        int hasNext = (i < 2) ? 1 : 0;
        k_step<<<nB_st, 256, 0, stream>>>(x, m_cur, m_nxt, xg_cur, batch, indptr, ssrc,
                                          wcat + OFF_Wa + i * 3072, wcat + OFF_ba + i * 32,
                                          wcat + OFF_Wg + i * 32, wcat + OFF_bg + i,
                                          wcat + OFF_Wa1, wcat + OFF_ba1,
                                          wcat + OFF_Wf + i * 1024, wcat + OFF_bf + i * 32,
                                          wcat + OFF_Wm + (i + 1) * 1024,
                                          wcat + OFF_bm + (i + 1) * 32,
                                          la1, U, S, N, hasNext);
        k_gupd<<<(GG * 32 + 255) / 256, 256, 0, stream>>>(U, S, xg_cur,
                                                          wcat + OFF_Wt + i * 2048,
                                                          wcat + OFF_bt + i * 32, xg_nxt);
        float* tmp = xg_cur; xg_cur = xg_nxt; xg_nxt = tmp;
        __hip_bfloat16* tm = m_cur; m_cur = m_nxt; m_nxt = tm;
    }

    k_final<<<GG, 256, 0, stream>>>(la1, goff, xg_cur, W_v, b_v, W_a0, b_a0,
                                    d_out, N, dtf);
}